// Round 11
// baseline (635.808 us; speedup 1.0000x reference)
//
#include <hip/hip_runtime.h>
#include <hip/hip_fp16.h>

// RandDCGRUCell on MI355X.
// B=64, N=2000, IN_DIM=2, U=64, D=66, NSUP=2, K=2, M=5.
// R10 post-mortem: k_projm 85us; MFMA ~6us, A-traffic 98MB, but every wave
// re-loaded the FULL 98KB W fragment array from L2 (8000 waves x 98KB =
// 786 MB L2 traffic) -> L2/latency bound. R11: W staged ONCE per block in
// LDS (49,152B = 4 ot x 12 k0 x 1KB), 2 nodes per block, mode0 runs two
// ot-half stages (stage-2 A re-read is L2-hot). W requests drop ~8x and
// move to ds_read_b128. SpMM chain untouched.

#define N_NODES 2000
#define BATCH   64
#define MMATS   5
#define ELLW    128
#define NSTRIDE 1536            // dwords per (cc, n): 48 kb * 32
#define SLICE_DW ((size_t)N_NODES * NSTRIDE)   // dwords per chunk (3,072,000)
#define PLANE_OFF(p) ((p)*288)  // dword offset of plane p within (cc,n)

typedef __half h16;
typedef _Float16 f16x8 __attribute__((ext_vector_type(8)));
typedef float    f32x4 __attribute__((ext_vector_type(4)));

__device__ __forceinline__ __half2 f2h2(float a, float b) {
  __half2 r; r.x = __float2half_rn(a); r.y = __float2half_rn(b); return r;
}
__device__ __forceinline__ unsigned int packh(float a, float b) {
  __half2 h = f2h2(a, b);
  return __builtin_bit_cast(unsigned int, h);
}
__device__ __forceinline__ float2 u2f2(unsigned int u) {
  return __half22float2(__builtin_bit_cast(__half2, u));
}
__device__ __forceinline__ float fexp2(float x) {
#if __has_builtin(__builtin_amdgcn_exp2f)
  return __builtin_amdgcn_exp2f(x);
#else
  return exp2f(x);
#endif
}
__device__ __forceinline__ float frcp(float x) {
#if __has_builtin(__builtin_amdgcn_rcpf)
  return __builtin_amdgcn_rcpf(x);
#else
  return 1.f/x;
#endif
}
#define LOG2E 1.44269504088896f
__device__ __forceinline__ float fsigmoid(float x) {
  return frcp(1.f + fexp2(-LOG2E*x));
}
__device__ __forceinline__ float ftanh(float x) {
  return 1.f - 2.f*frcp(1.f + fexp2((2.f*LOG2E)*x));
}

// ---------------- weights: fragment-order swizzled fp16 W -----------
// Wz[((ot*12 + k0)*64 + lane)*8 + j] = W[k][o], k = k0*32 + (lane>>4)*8 + j,
// o = ot*16 + (lane&15); k = 72p + d (plane-major), d<66 valid, k>=360 -> 0.
__global__ __launch_bounds__(256) void k_weights(
    const float* __restrict__ mu_w_ru, const float* __restrict__ ls_w_ru, const float* __restrict__ eps_w_ru,
    const float* __restrict__ mu_b_ru, const float* __restrict__ ls_b_ru, const float* __restrict__ eps_b_ru,
    const float* __restrict__ mu_w_c,  const float* __restrict__ ls_w_c,  const float* __restrict__ eps_w_c,
    const float* __restrict__ mu_b_c,  const float* __restrict__ ls_b_c,  const float* __restrict__ eps_b_c,
    h16* __restrict__ Wzru, float* __restrict__ bru,
    h16* __restrict__ Wzc,  float* __restrict__ bc)
{
  int idx = blockIdx.x*256 + threadIdx.x;
  const int n_ru = 8*12*64*8;   // 49152
  const int n_c  = 4*12*64*8;   // 24576
  if (idx < n_ru) {
    int j = idx & 7, ln = (idx >> 3) & 63, rest = idx >> 9;
    int k = (rest % 12)*32 + (ln >> 4)*8 + j;
    int o = (rest / 12)*16 + (ln & 15);
    float wv = 0.f;
    if (k < 360) {
      int p = k/72, d = k - p*72;
      if (d < 66) {
        int r = (d*MMATS + p)*128 + o;
        wv = mu_w_ru[r] + expf(ls_w_ru[r]) * eps_w_ru[r];
      }
    }
    Wzru[idx] = __float2half_rn(wv);
  } else if (idx < n_ru + n_c) {
    int i = idx - n_ru;
    int j = i & 7, ln = (i >> 3) & 63, rest = i >> 9;
    int k = (rest % 12)*32 + (ln >> 4)*8 + j;
    int o = (rest / 12)*16 + (ln & 15);
    float wv = 0.f;
    if (k < 360) {
      int p = k/72, d = k - p*72;
      if (d < 66) {
        int r = (d*MMATS + p)*64 + o;
        wv = mu_w_c[r] + expf(ls_w_c[r]) * eps_w_c[r];
      }
    }
    Wzc[i] = __float2half_rn(wv);
  } else if (idx < n_ru + n_c + 128) {
    int i = idx - n_ru - n_c;
    bru[i] = mu_b_ru[i] + expf(ls_b_ru[i]) * eps_b_ru[i];
  } else if (idx < n_ru + n_c + 128 + 64) {
    int i = idx - n_ru - n_c - 128;
    bc[i] = mu_b_c[i] + expf(ls_b_c[i]) * eps_b_c[i];
  }
}

// ---------------- ELL build (order within row irrelevant for a sum) --
__global__ __launch_bounds__(256) void k_ell(
    const float* __restrict__ supp, unsigned short* __restrict__ cols,
    float* __restrict__ vals, int* __restrict__ cnt)
{
  int j = blockIdx.x*256 + threadIdx.x;
  if (j >= N_NODES) return;
  int n = blockIdx.y, s = blockIdx.z;
  int r = s*N_NODES + n;
  float v = supp[(size_t)r*N_NODES + j];
  if (v != 0.f) {
    int p = atomicAdd(cnt + r, 1);
    if (p < ELLW) {
      cols[(size_t)r*ELLW + p] = (unsigned short)j;
      vals[(size_t)r*ELLW + p] = v;
    }
  }
}

// ---------------- build x0 plane (p=0) + zero pad blocks -------------
// XA micro-block layout per (cc,n): [48kb][8bs][8k] halfs (1536 dwords).
__global__ __launch_bounds__(256) void k_build0(
    const float* __restrict__ inp, const float* __restrict__ hx,
    const h16* __restrict__ VALr, unsigned int* __restrict__ XAu, int mode)
{
  const int n = blockIdx.x;
  const int g = threadIdx.x >> 5, tt = threadIdx.x & 31;
  const int b = g*8 + (tt >> 2);
  unsigned int* dst = XAu + (size_t)g*SLICE_DW + (size_t)n*NSTRIDE;
  #pragma unroll
  for (int kb = 0; kb < 9; ++kb) {
    int d0 = kb*8 + 2*(tt & 3);
    float v[2];
    #pragma unroll
    for (int q = 0; q < 2; ++q) {
      int d = d0 + q;
      float x = 0.f;
      if (d < 2) {
        x = inp[(size_t)b*(N_NODES*2) + n*2 + d];
      } else if (d < 66) {
        x = hx[(size_t)b*(N_NODES*64) + n*64 + (d-2)];
        if (mode == 1) x *= __half2float(VALr[(size_t)n*8192 + b*128 + (d-2)]);
      }
      v[q] = x;
    }
    dst[kb*32 + tt] = packh(v[0], v[1]);
  }
  dst[45*32 + tt] = 0u;  // pad kbs 45..47 (k in [360,384))
  dst[46*32 + tt] = 0u;
  dst[47*32 + tt] = 0u;
}

// ---------------- SpMM: plane(1+2s) = S_s @ plane0 -------------------
// Regular stores: planes 1/3 must stay L2-hot for k_cheb's gathers.
__global__ __launch_bounds__(256) void k_spmm(
    unsigned int* __restrict__ XAu, const unsigned short* __restrict__ cols,
    const float* __restrict__ vals, const int* __restrict__ cnt)
{
  const int cc = blockIdx.x;
  const int r  = blockIdx.y*8 + (threadIdx.x >> 5);
  const int tt = threadIdx.x & 31;
  const int s  = (r >= N_NODES) ? 1 : 0;
  const int n  = r - s*N_NODES;
  int c = cnt[r]; if (c > ELLW) c = ELLW;
  const unsigned short* cp = cols + (size_t)r*ELLW;
  const float*          vp = vals + (size_t)r*ELLW;
  const unsigned int* slice = XAu + (size_t)cc*SLICE_DW;   // plane 0 offset 0
  float2 acc[9];
  #pragma unroll
  for (int i = 0; i < 9; ++i) acc[i] = make_float2(0.f, 0.f);
  for (int k = 0; k < c; ++k) {
    int j = cp[k]; float v = vp[k];
    const unsigned int* s0 = slice + (size_t)j*NSTRIDE + tt;
    #pragma unroll
    for (int i = 0; i < 9; ++i) {
      float2 f = u2f2(s0[i*32]);
      acc[i].x = fmaf(v, f.x, acc[i].x);
      acc[i].y = fmaf(v, f.y, acc[i].y);
    }
  }
  unsigned int* dp = XAu + (size_t)cc*SLICE_DW + (size_t)n*NSTRIDE
                   + PLANE_OFF(1 + 2*s) + tt;
  #pragma unroll
  for (int i = 0; i < 9; ++i)
    dp[i*32] = packh(acc[i].x, acc[i].y);
}

// ---------------- Chebyshev: plane(2+2s) = 2*S_s@plane(1+2s) - plane0 -
__global__ __launch_bounds__(256) void k_cheb(
    unsigned int* __restrict__ XAu, const unsigned short* __restrict__ cols,
    const float* __restrict__ vals, const int* __restrict__ cnt)
{
  const int cc = blockIdx.x;
  const int r  = blockIdx.y*8 + (threadIdx.x >> 5);
  const int tt = threadIdx.x & 31;
  const int s  = (r >= N_NODES) ? 1 : 0;
  const int n  = r - s*N_NODES;
  int c = cnt[r]; if (c > ELLW) c = ELLW;
  const unsigned short* cp = cols + (size_t)r*ELLW;
  const float*          vp = vals + (size_t)r*ELLW;
  const unsigned int* slice = XAu + (size_t)cc*SLICE_DW + PLANE_OFF(1 + 2*s);
  float2 acc[9];
  #pragma unroll
  for (int i = 0; i < 9; ++i) acc[i] = make_float2(0.f, 0.f);
  for (int k = 0; k < c; ++k) {
    int j = cp[k]; float v = vp[k];
    const unsigned int* s0 = slice + (size_t)j*NSTRIDE + tt;
    #pragma unroll
    for (int i = 0; i < 9; ++i) {
      float2 f = u2f2(s0[i*32]);
      acc[i].x = fmaf(v, f.x, acc[i].x);
      acc[i].y = fmaf(v, f.y, acc[i].y);
    }
  }
  const unsigned int* xp = XAu + (size_t)cc*SLICE_DW + (size_t)n*NSTRIDE + tt; // plane 0
  unsigned int* dp = XAu + (size_t)cc*SLICE_DW + (size_t)n*NSTRIDE
                   + PLANE_OFF(2 + 2*s) + tt;
  #pragma unroll
  for (int i = 0; i < 9; ++i) {
    float2 f0 = u2f2(__builtin_nontemporal_load(xp + i*32));
    __builtin_nontemporal_store(packh(2.f*acc[i].x - f0.x, 2.f*acc[i].y - f0.y),
                                dp + i*32);
  }
}

// ---------------- projection via MFMA, W in LDS, 2 nodes/block -------
// Block blk covers nodes {2blk, 2blk+1}. LDS holds 4 ot-tiles of W frags
// (49,152 B). mode 0: two stages (o-halves). Wave w owns b-rows [16w,16w+16).
// mode 0: VAL[n][b][o] = sigmoid(acc+bias) fp16
// mode 1: out = u*hx + (1-u)*tanh(acc+bias) fp32
__global__ __launch_bounds__(256) void k_projm(
    const unsigned int* __restrict__ XAu, const h16* __restrict__ Wz,
    const float* __restrict__ bias, h16* __restrict__ VAL,
    const float* __restrict__ hx, const h16* __restrict__ VALu,
    float* __restrict__ out, int mode)
{
  __shared__ h16 WL[4*12*64*8];            // 49,152 B
  const int n0 = blockIdx.x*2;
  const int t = threadIdx.x;
  const int w = t >> 6, lane = t & 63;
  const int quad = lane >> 4, lr = lane & 15;
  const int b0 = w*16;
  const int cc = 2*w + (lr >> 3), bs = lr & 7;
  const int nst = mode ? 1 : 2;

  for (int st = 0; st < nst; ++st) {
    __syncthreads();                       // prior-stage readers done
    {
      uint4* dl = (uint4*)WL;
      const uint4* sg = (const uint4*)Wz + st*3072;
      for (int i = t; i < 3072; i += 256) dl[i] = sg[i];
    }
    __syncthreads();

    for (int ni = 0; ni < 2; ++ni) {
      const int n = n0 + ni;
      const h16* abase = (const h16*)(XAu + (size_t)cc*SLICE_DW + (size_t)n*NSTRIDE)
                       + bs*8 + quad*64;
      f32x4 acc[4];
      #pragma unroll
      for (int i = 0; i < 4; ++i) acc[i] = (f32x4){0.f,0.f,0.f,0.f};

      for (int k0 = 0; k0 < 12; ++k0) {
        f16x8 a = *(const f16x8*)(abase + k0*256);
        #pragma unroll
        for (int ot = 0; ot < 4; ++ot) {
          f16x8 bf = *(const f16x8*)(WL + ((ot*12 + k0)*64 + lane)*8);
          acc[ot] = __builtin_amdgcn_mfma_f32_16x16x32_f16(a, bf, acc[ot], 0, 0, 0);
        }
      }

      if (mode == 0) {
        #pragma unroll
        for (int ot = 0; ot < 4; ++ot) {
          int o = st*64 + ot*16 + lr;
          float bia = bias[o];
          #pragma unroll
          for (int r = 0; r < 4; ++r) {
            int b = b0 + quad*4 + r;
            VAL[(size_t)n*8192 + b*128 + o] = __float2half_rn(fsigmoid(acc[ot][r] + bia));
          }
        }
      } else {
        #pragma unroll
        for (int ot = 0; ot < 4; ++ot) {
          int o = ot*16 + lr;
          float bia = bias[o];
          #pragma unroll
          for (int r = 0; r < 4; ++r) {
            int b = b0 + quad*4 + r;
            float cv = ftanh(acc[ot][r] + bia);
            float u  = __half2float(VALu[(size_t)n*8192 + b*128 + 64 + o]);
            float h  = hx[(size_t)b*(N_NODES*64) + n*64 + o];
            out[(size_t)b*(N_NODES*64) + n*64 + o] = u*h + (1.f - u)*cv;
          }
        }
      }
    }
  }
}

extern "C" void kernel_launch(void* const* d_in, const int* in_sizes, int n_in,
                              void* d_out, int out_size, void* d_ws, size_t ws_size,
                              hipStream_t stream)
{
  const float* inp      = (const float*)d_in[0];
  const float* hx       = (const float*)d_in[1];
  const float* supp     = (const float*)d_in[2];
  const float* mu_w_ru  = (const float*)d_in[3];
  const float* ls_w_ru  = (const float*)d_in[4];
  const float* mu_b_ru  = (const float*)d_in[5];
  const float* ls_b_ru  = (const float*)d_in[6];
  const float* eps_w_ru = (const float*)d_in[7];
  const float* eps_b_ru = (const float*)d_in[8];
  const float* mu_w_c   = (const float*)d_in[9];
  const float* ls_w_c   = (const float*)d_in[10];
  const float* mu_b_c   = (const float*)d_in[11];
  const float* ls_b_c   = (const float*)d_in[12];
  const float* eps_w_c  = (const float*)d_in[13];
  const float* eps_b_c  = (const float*)d_in[14];
  float* out = (float*)d_out;

  char* wsp = (char*)d_ws;
  size_t off = 0;
  auto take = [&](size_t bytes) -> void* {
    void* p = wsp + off;
    off = (off + bytes + 255) & ~(size_t)255;
    return p;
  };
  unsigned int* XAu = (unsigned int*)take(8*SLICE_DW*sizeof(unsigned int)); // 98.3 MB
  h16*   VAL = (h16*)  take((size_t)N_NODES*8192*sizeof(h16));       // 32.8 MB
  h16*   Wzru= (h16*)  take((size_t)8*12*64*8*sizeof(h16));          // 98.3 KB
  h16*   Wzc = (h16*)  take((size_t)4*12*64*8*sizeof(h16));          // 49.2 KB
  float* bru = (float*)take(128*sizeof(float));
  float* bc  = (float*)take(64*sizeof(float));
  unsigned short* ellc = (unsigned short*)take((size_t)2*N_NODES*ELLW*sizeof(unsigned short));
  float* ellv= (float*)take((size_t)2*N_NODES*ELLW*sizeof(float));
  int*   cnt = (int*)  take((size_t)2*N_NODES*sizeof(int));
  // total ~134.5 MB (fits: R9/R10 ran at this footprint)
  (void)ws_size;

  hipMemsetAsync(cnt, 0, (size_t)2*N_NODES*sizeof(int), stream);
  k_weights<<<289, 256, 0, stream>>>(mu_w_ru, ls_w_ru, eps_w_ru,
                                     mu_b_ru, ls_b_ru, eps_b_ru,
                                     mu_w_c, ls_w_c, eps_w_c,
                                     mu_b_c, ls_b_c, eps_b_c,
                                     Wzru, bru, Wzc, bc);
  k_ell<<<dim3(8, N_NODES, 2), 256, 0, stream>>>(supp, ellc, ellv, cnt);

  for (int pass = 0; pass < 2; ++pass) {
    k_build0<<<N_NODES, 256, 0, stream>>>(inp, hx, VAL, XAu, pass);
    k_spmm <<<dim3(8, 500), 256, 0, stream>>>(XAu, ellc, ellv, cnt);
    k_cheb <<<dim3(8, 500), 256, 0, stream>>>(XAu, ellc, ellv, cnt);
    if (pass == 0)
      k_projm<<<N_NODES/2, 256, 0, stream>>>(XAu, Wzru, bru, VAL,
                                             nullptr, nullptr, nullptr, 0);
    else
      k_projm<<<N_NODES/2, 256, 0, stream>>>(XAu, Wzc, bc, nullptr,
                                             hx, VAL, out, 1);
  }
}

// Round 12
// 588.977 us; speedup vs baseline: 1.0795x; 1.0795x over previous
//
#include <hip/hip_runtime.h>
#include <hip/hip_fp16.h>

// RandDCGRUCell on MI355X.
// B=64, N=2000, IN_DIM=2, U=64, D=66, NSUP=2, K=2, M=5.
// R11 post-mortem: gather chain (k_spmm/k_cheb ~78us each) is critical path;
// 2.4x above the 33us per-XCD L2 floor. Cause: per-nnz dependent chain
// load cols[k] -> addr -> 9 data loads. R12: preload each ELL row's
// (cols,vals) into registers (2 coalesced loads per group) and broadcast
// per-j via __shfl(width=32): j-loop becomes pure back-to-back data loads.
// (Dense-MFMA alternative rejected: 75 GF/dispatch = slower at any
// realistic TF.) Everything else unchanged.

#define N_NODES 2000
#define BATCH   64
#define MMATS   5
#define ELLW    128
#define NSTRIDE 1536            // dwords per (cc, n): 48 kb * 32
#define SLICE_DW ((size_t)N_NODES * NSTRIDE)   // dwords per chunk (3,072,000)
#define PLANE_OFF(p) ((p)*288)  // dword offset of plane p within (cc,n)

typedef __half h16;
typedef _Float16 f16x8 __attribute__((ext_vector_type(8)));
typedef float    f32x4 __attribute__((ext_vector_type(4)));

__device__ __forceinline__ __half2 f2h2(float a, float b) {
  __half2 r; r.x = __float2half_rn(a); r.y = __float2half_rn(b); return r;
}
__device__ __forceinline__ unsigned int packh(float a, float b) {
  __half2 h = f2h2(a, b);
  return __builtin_bit_cast(unsigned int, h);
}
__device__ __forceinline__ float2 u2f2(unsigned int u) {
  return __half22float2(__builtin_bit_cast(__half2, u));
}
__device__ __forceinline__ float fexp2(float x) {
#if __has_builtin(__builtin_amdgcn_exp2f)
  return __builtin_amdgcn_exp2f(x);
#else
  return exp2f(x);
#endif
}
__device__ __forceinline__ float frcp(float x) {
#if __has_builtin(__builtin_amdgcn_rcpf)
  return __builtin_amdgcn_rcpf(x);
#else
  return 1.f/x;
#endif
}
#define LOG2E 1.44269504088896f
__device__ __forceinline__ float fsigmoid(float x) {
  return frcp(1.f + fexp2(-LOG2E*x));
}
__device__ __forceinline__ float ftanh(float x) {
  return 1.f - 2.f*frcp(1.f + fexp2((2.f*LOG2E)*x));
}

// ---------------- weights: fragment-order swizzled fp16 W -----------
// Wz[((ot*12 + k0)*64 + lane)*8 + j] = W[k][o], k = k0*32 + (lane>>4)*8 + j,
// o = ot*16 + (lane&15); k = 72p + d (plane-major), d<66 valid, k>=360 -> 0.
__global__ __launch_bounds__(256) void k_weights(
    const float* __restrict__ mu_w_ru, const float* __restrict__ ls_w_ru, const float* __restrict__ eps_w_ru,
    const float* __restrict__ mu_b_ru, const float* __restrict__ ls_b_ru, const float* __restrict__ eps_b_ru,
    const float* __restrict__ mu_w_c,  const float* __restrict__ ls_w_c,  const float* __restrict__ eps_w_c,
    const float* __restrict__ mu_b_c,  const float* __restrict__ ls_b_c,  const float* __restrict__ eps_b_c,
    h16* __restrict__ Wzru, float* __restrict__ bru,
    h16* __restrict__ Wzc,  float* __restrict__ bc)
{
  int idx = blockIdx.x*256 + threadIdx.x;
  const int n_ru = 8*12*64*8;   // 49152
  const int n_c  = 4*12*64*8;   // 24576
  if (idx < n_ru) {
    int j = idx & 7, ln = (idx >> 3) & 63, rest = idx >> 9;
    int k = (rest % 12)*32 + (ln >> 4)*8 + j;
    int o = (rest / 12)*16 + (ln & 15);
    float wv = 0.f;
    if (k < 360) {
      int p = k/72, d = k - p*72;
      if (d < 66) {
        int r = (d*MMATS + p)*128 + o;
        wv = mu_w_ru[r] + expf(ls_w_ru[r]) * eps_w_ru[r];
      }
    }
    Wzru[idx] = __float2half_rn(wv);
  } else if (idx < n_ru + n_c) {
    int i = idx - n_ru;
    int j = i & 7, ln = (i >> 3) & 63, rest = i >> 9;
    int k = (rest % 12)*32 + (ln >> 4)*8 + j;
    int o = (rest / 12)*16 + (ln & 15);
    float wv = 0.f;
    if (k < 360) {
      int p = k/72, d = k - p*72;
      if (d < 66) {
        int r = (d*MMATS + p)*64 + o;
        wv = mu_w_c[r] + expf(ls_w_c[r]) * eps_w_c[r];
      }
    }
    Wzc[i] = __float2half_rn(wv);
  } else if (idx < n_ru + n_c + 128) {
    int i = idx - n_ru - n_c;
    bru[i] = mu_b_ru[i] + expf(ls_b_ru[i]) * eps_b_ru[i];
  } else if (idx < n_ru + n_c + 128 + 64) {
    int i = idx - n_ru - n_c - 128;
    bc[i] = mu_b_c[i] + expf(ls_b_c[i]) * eps_b_c[i];
  }
}

// ---------------- ELL build (order within row irrelevant for a sum) --
__global__ __launch_bounds__(256) void k_ell(
    const float* __restrict__ supp, unsigned short* __restrict__ cols,
    float* __restrict__ vals, int* __restrict__ cnt)
{
  int j = blockIdx.x*256 + threadIdx.x;
  if (j >= N_NODES) return;
  int n = blockIdx.y, s = blockIdx.z;
  int r = s*N_NODES + n;
  float v = supp[(size_t)r*N_NODES + j];
  if (v != 0.f) {
    int p = atomicAdd(cnt + r, 1);
    if (p < ELLW) {
      cols[(size_t)r*ELLW + p] = (unsigned short)j;
      vals[(size_t)r*ELLW + p] = v;
    }
  }
}

// ---------------- build x0 plane (p=0) + zero pad blocks -------------
// XA micro-block layout per (cc,n): [48kb][8bs][8k] halfs (1536 dwords).
__global__ __launch_bounds__(256) void k_build0(
    const float* __restrict__ inp, const float* __restrict__ hx,
    const h16* __restrict__ VALr, unsigned int* __restrict__ XAu, int mode)
{
  const int n = blockIdx.x;
  const int g = threadIdx.x >> 5, tt = threadIdx.x & 31;
  const int b = g*8 + (tt >> 2);
  unsigned int* dst = XAu + (size_t)g*SLICE_DW + (size_t)n*NSTRIDE;
  #pragma unroll
  for (int kb = 0; kb < 9; ++kb) {
    int d0 = kb*8 + 2*(tt & 3);
    float v[2];
    #pragma unroll
    for (int q = 0; q < 2; ++q) {
      int d = d0 + q;
      float x = 0.f;
      if (d < 2) {
        x = inp[(size_t)b*(N_NODES*2) + n*2 + d];
      } else if (d < 66) {
        x = hx[(size_t)b*(N_NODES*64) + n*64 + (d-2)];
        if (mode == 1) x *= __half2float(VALr[(size_t)n*8192 + b*128 + (d-2)]);
      }
      v[q] = x;
    }
    dst[kb*32 + tt] = packh(v[0], v[1]);
  }
  dst[45*32 + tt] = 0u;  // pad kbs 45..47 (k in [360,384))
  dst[46*32 + tt] = 0u;
  dst[47*32 + tt] = 0u;
}

// ---------------- SpMM: plane(1+2s) = S_s @ plane0 -------------------
// ELL row preloaded to registers, __shfl-broadcast per j.
__global__ __launch_bounds__(256) void k_spmm(
    unsigned int* __restrict__ XAu, const unsigned short* __restrict__ cols,
    const float* __restrict__ vals, const int* __restrict__ cnt)
{
  const int cc = blockIdx.x;
  const int r  = blockIdx.y*8 + (threadIdx.x >> 5);
  const int tt = threadIdx.x & 31;
  const int s  = (r >= N_NODES) ? 1 : 0;
  const int n  = r - s*N_NODES;
  int c = cnt[r]; if (c > ELLW) c = ELLW;
  const unsigned short* cp = cols + (size_t)r*ELLW;
  const float*          vp = vals + (size_t)r*ELLW;
  int   pc0 = cp[tt],    pc1 = cp[32 + tt];
  float pv0 = vp[tt],    pv1 = vp[32 + tt];
  const unsigned int* slice = XAu + (size_t)cc*SLICE_DW;   // plane 0 offset 0
  float2 acc[9];
  #pragma unroll
  for (int i = 0; i < 9; ++i) acc[i] = make_float2(0.f, 0.f);
  const int c0 = c < 32 ? c : 32;
  const int c1 = c < 64 ? c : 64;
  for (int k = 0; k < c0; ++k) {
    int j = __shfl(pc0, k, 32); float v = __shfl(pv0, k, 32);
    const unsigned int* s0 = slice + (size_t)j*NSTRIDE + tt;
    #pragma unroll
    for (int i = 0; i < 9; ++i) {
      float2 f = u2f2(s0[i*32]);
      acc[i].x = fmaf(v, f.x, acc[i].x);
      acc[i].y = fmaf(v, f.y, acc[i].y);
    }
  }
  for (int k = 32; k < c1; ++k) {
    int j = __shfl(pc1, k - 32, 32); float v = __shfl(pv1, k - 32, 32);
    const unsigned int* s0 = slice + (size_t)j*NSTRIDE + tt;
    #pragma unroll
    for (int i = 0; i < 9; ++i) {
      float2 f = u2f2(s0[i*32]);
      acc[i].x = fmaf(v, f.x, acc[i].x);
      acc[i].y = fmaf(v, f.y, acc[i].y);
    }
  }
  for (int k = 64; k < c; ++k) {           // statistically near-never
    int j = cp[k]; float v = vp[k];
    const unsigned int* s0 = slice + (size_t)j*NSTRIDE + tt;
    #pragma unroll
    for (int i = 0; i < 9; ++i) {
      float2 f = u2f2(s0[i*32]);
      acc[i].x = fmaf(v, f.x, acc[i].x);
      acc[i].y = fmaf(v, f.y, acc[i].y);
    }
  }
  unsigned int* dp = XAu + (size_t)cc*SLICE_DW + (size_t)n*NSTRIDE
                   + PLANE_OFF(1 + 2*s) + tt;
  #pragma unroll
  for (int i = 0; i < 9; ++i)
    dp[i*32] = packh(acc[i].x, acc[i].y);
}

// ---------------- Chebyshev: plane(2+2s) = 2*S_s@plane(1+2s) - plane0 -
__global__ __launch_bounds__(256) void k_cheb(
    unsigned int* __restrict__ XAu, const unsigned short* __restrict__ cols,
    const float* __restrict__ vals, const int* __restrict__ cnt)
{
  const int cc = blockIdx.x;
  const int r  = blockIdx.y*8 + (threadIdx.x >> 5);
  const int tt = threadIdx.x & 31;
  const int s  = (r >= N_NODES) ? 1 : 0;
  const int n  = r - s*N_NODES;
  int c = cnt[r]; if (c > ELLW) c = ELLW;
  const unsigned short* cp = cols + (size_t)r*ELLW;
  const float*          vp = vals + (size_t)r*ELLW;
  int   pc0 = cp[tt],    pc1 = cp[32 + tt];
  float pv0 = vp[tt],    pv1 = vp[32 + tt];
  const unsigned int* slice = XAu + (size_t)cc*SLICE_DW + PLANE_OFF(1 + 2*s);
  float2 acc[9];
  #pragma unroll
  for (int i = 0; i < 9; ++i) acc[i] = make_float2(0.f, 0.f);
  const int c0 = c < 32 ? c : 32;
  const int c1 = c < 64 ? c : 64;
  for (int k = 0; k < c0; ++k) {
    int j = __shfl(pc0, k, 32); float v = __shfl(pv0, k, 32);
    const unsigned int* s0 = slice + (size_t)j*NSTRIDE + tt;
    #pragma unroll
    for (int i = 0; i < 9; ++i) {
      float2 f = u2f2(s0[i*32]);
      acc[i].x = fmaf(v, f.x, acc[i].x);
      acc[i].y = fmaf(v, f.y, acc[i].y);
    }
  }
  for (int k = 32; k < c1; ++k) {
    int j = __shfl(pc1, k - 32, 32); float v = __shfl(pv1, k - 32, 32);
    const unsigned int* s0 = slice + (size_t)j*NSTRIDE + tt;
    #pragma unroll
    for (int i = 0; i < 9; ++i) {
      float2 f = u2f2(s0[i*32]);
      acc[i].x = fmaf(v, f.x, acc[i].x);
      acc[i].y = fmaf(v, f.y, acc[i].y);
    }
  }
  for (int k = 64; k < c; ++k) {
    int j = cp[k]; float v = vp[k];
    const unsigned int* s0 = slice + (size_t)j*NSTRIDE + tt;
    #pragma unroll
    for (int i = 0; i < 9; ++i) {
      float2 f = u2f2(s0[i*32]);
      acc[i].x = fmaf(v, f.x, acc[i].x);
      acc[i].y = fmaf(v, f.y, acc[i].y);
    }
  }
  const unsigned int* xp = XAu + (size_t)cc*SLICE_DW + (size_t)n*NSTRIDE + tt; // plane 0
  unsigned int* dp = XAu + (size_t)cc*SLICE_DW + (size_t)n*NSTRIDE
                   + PLANE_OFF(2 + 2*s) + tt;
  #pragma unroll
  for (int i = 0; i < 9; ++i) {
    float2 f0 = u2f2(__builtin_nontemporal_load(xp + i*32));
    __builtin_nontemporal_store(packh(2.f*acc[i].x - f0.x, 2.f*acc[i].y - f0.y),
                                dp + i*32);
  }
}

// ---------------- projection via MFMA, W in LDS, 2 nodes/block -------
// Block blk covers nodes {2blk, 2blk+1}. LDS holds 4 ot-tiles of W frags
// (49,152 B). mode 0: two stages (o-halves). Wave w owns b-rows [16w,16w+16).
// mode 0: VAL[n][b][o] = sigmoid(acc+bias) fp16
// mode 1: out = u*hx + (1-u)*tanh(acc+bias) fp32
__global__ __launch_bounds__(256) void k_projm(
    const unsigned int* __restrict__ XAu, const h16* __restrict__ Wz,
    const float* __restrict__ bias, h16* __restrict__ VAL,
    const float* __restrict__ hx, const h16* __restrict__ VALu,
    float* __restrict__ out, int mode)
{
  __shared__ h16 WL[4*12*64*8];            // 49,152 B
  const int n0 = blockIdx.x*2;
  const int t = threadIdx.x;
  const int w = t >> 6, lane = t & 63;
  const int quad = lane >> 4, lr = lane & 15;
  const int b0 = w*16;
  const int cc = 2*w + (lr >> 3), bs = lr & 7;
  const int nst = mode ? 1 : 2;

  for (int st = 0; st < nst; ++st) {
    __syncthreads();                       // prior-stage readers done
    {
      uint4* dl = (uint4*)WL;
      const uint4* sg = (const uint4*)Wz + st*3072;
      for (int i = t; i < 3072; i += 256) dl[i] = sg[i];
    }
    __syncthreads();

    for (int ni = 0; ni < 2; ++ni) {
      const int n = n0 + ni;
      const h16* abase = (const h16*)(XAu + (size_t)cc*SLICE_DW + (size_t)n*NSTRIDE)
                       + bs*8 + quad*64;
      f32x4 acc[4];
      #pragma unroll
      for (int i = 0; i < 4; ++i) acc[i] = (f32x4){0.f,0.f,0.f,0.f};

      for (int k0 = 0; k0 < 12; ++k0) {
        f16x8 a = *(const f16x8*)(abase + k0*256);
        #pragma unroll
        for (int ot = 0; ot < 4; ++ot) {
          f16x8 bf = *(const f16x8*)(WL + ((ot*12 + k0)*64 + lane)*8);
          acc[ot] = __builtin_amdgcn_mfma_f32_16x16x32_f16(a, bf, acc[ot], 0, 0, 0);
        }
      }

      if (mode == 0) {
        #pragma unroll
        for (int ot = 0; ot < 4; ++ot) {
          int o = st*64 + ot*16 + lr;
          float bia = bias[o];
          #pragma unroll
          for (int r = 0; r < 4; ++r) {
            int b = b0 + quad*4 + r;
            VAL[(size_t)n*8192 + b*128 + o] = __float2half_rn(fsigmoid(acc[ot][r] + bia));
          }
        }
      } else {
        #pragma unroll
        for (int ot = 0; ot < 4; ++ot) {
          int o = ot*16 + lr;
          float bia = bias[o];
          #pragma unroll
          for (int r = 0; r < 4; ++r) {
            int b = b0 + quad*4 + r;
            float cv = ftanh(acc[ot][r] + bia);
            float u  = __half2float(VALu[(size_t)n*8192 + b*128 + 64 + o]);
            float h  = hx[(size_t)b*(N_NODES*64) + n*64 + o];
            out[(size_t)b*(N_NODES*64) + n*64 + o] = u*h + (1.f - u)*cv;
          }
        }
      }
    }
  }
}

extern "C" void kernel_launch(void* const* d_in, const int* in_sizes, int n_in,
                              void* d_out, int out_size, void* d_ws, size_t ws_size,
                              hipStream_t stream)
{
  const float* inp      = (const float*)d_in[0];
  const float* hx       = (const float*)d_in[1];
  const float* supp     = (const float*)d_in[2];
  const float* mu_w_ru  = (const float*)d_in[3];
  const float* ls_w_ru  = (const float*)d_in[4];
  const float* mu_b_ru  = (const float*)d_in[5];
  const float* ls_b_ru  = (const float*)d_in[6];
  const float* eps_w_ru = (const float*)d_in[7];
  const float* eps_b_ru = (const float*)d_in[8];
  const float* mu_w_c   = (const float*)d_in[9];
  const float* ls_w_c   = (const float*)d_in[10];
  const float* mu_b_c   = (const float*)d_in[11];
  const float* ls_b_c   = (const float*)d_in[12];
  const float* eps_w_c  = (const float*)d_in[13];
  const float* eps_b_c  = (const float*)d_in[14];
  float* out = (float*)d_out;

  char* wsp = (char*)d_ws;
  size_t off = 0;
  auto take = [&](size_t bytes) -> void* {
    void* p = wsp + off;
    off = (off + bytes + 255) & ~(size_t)255;
    return p;
  };
  unsigned int* XAu = (unsigned int*)take(8*SLICE_DW*sizeof(unsigned int)); // 98.3 MB
  h16*   VAL = (h16*)  take((size_t)N_NODES*8192*sizeof(h16));       // 32.8 MB
  h16*   Wzru= (h16*)  take((size_t)8*12*64*8*sizeof(h16));          // 98.3 KB
  h16*   Wzc = (h16*)  take((size_t)4*12*64*8*sizeof(h16));          // 49.2 KB
  float* bru = (float*)take(128*sizeof(float));
  float* bc  = (float*)take(64*sizeof(float));
  unsigned short* ellc = (unsigned short*)take((size_t)2*N_NODES*ELLW*sizeof(unsigned short));
  float* ellv= (float*)take((size_t)2*N_NODES*ELLW*sizeof(float));
  int*   cnt = (int*)  take((size_t)2*N_NODES*sizeof(int));
  // total ~134.5 MB (fits: R9-R11 ran at this footprint)
  (void)ws_size;

  hipMemsetAsync(cnt, 0, (size_t)2*N_NODES*sizeof(int), stream);
  k_weights<<<289, 256, 0, stream>>>(mu_w_ru, ls_w_ru, eps_w_ru,
                                     mu_b_ru, ls_b_ru, eps_b_ru,
                                     mu_w_c, ls_w_c, eps_w_c,
                                     mu_b_c, ls_b_c, eps_b_c,
                                     Wzru, bru, Wzc, bc);
  k_ell<<<dim3(8, N_NODES, 2), 256, 0, stream>>>(supp, ellc, ellv, cnt);

  for (int pass = 0; pass < 2; ++pass) {
    k_build0<<<N_NODES, 256, 0, stream>>>(inp, hx, VAL, XAu, pass);
    k_spmm <<<dim3(8, 500), 256, 0, stream>>>(XAu, ellc, ellv, cnt);
    k_cheb <<<dim3(8, 500), 256, 0, stream>>>(XAu, ellc, ellv, cnt);
    if (pass == 0)
      k_projm<<<N_NODES/2, 256, 0, stream>>>(XAu, Wzru, bru, VAL,
                                             nullptr, nullptr, nullptr, 0);
    else
      k_projm<<<N_NODES/2, 256, 0, stream>>>(XAu, Wzc, bc, nullptr,
                                             hx, VAL, out, 1);
  }
}